// Round 7
// baseline (197.363 us; speedup 1.0000x reference)
//
#include <hip/hip_runtime.h>
#include <hip/hip_bf16.h>

typedef __attribute__((ext_vector_type(4))) float  f32x4;
typedef __attribute__((ext_vector_type(8))) short  short8;

#define EMBED 4096
#define LR    512
#define KSEL  128
#define BATCH 8192
#define NSLICE 8
#define KSLICE 512

__device__ __forceinline__ short f2bf(float x) {
  union { float f; unsigned u; } c; c.f = x;
  unsigned r = c.u + 0x7FFFu + ((c.u >> 16) & 1u);  // RNE
  return (short)(r >> 16);
}
__device__ __forceinline__ float bf2f(short s) {
  union { unsigned u; float f; } c; c.u = ((unsigned)(unsigned short)s) << 16;
  return c.f;
}
__device__ __forceinline__ void storept(float* p, float v) { *p = v; }
__device__ __forceinline__ void storept(short* p, float v) { *p = f2bf(v); }
__device__ __forceinline__ void loadpart(const float* p, f32x4& a, f32x4& b) {
  a += *(const f32x4*)p; b += *(const f32x4*)(p + 4);
}
__device__ __forceinline__ void loadpart(const short* p, f32x4& a, f32x4& b) {
  short8 v = *(const short8*)p;
  #pragma unroll
  for (int j = 0; j < 4; ++j) { a[j] += bf2f(v[j]); b[j] += bf2f(v[4 + j]); }
}

// K0: gather selected columns of W, emit two bf16 MFMA-packed layouts.
__global__ __launch_bounds__(256) void pack_w_kernel(
    const float* __restrict__ W, const int* __restrict__ sel,
    short* __restrict__ Wp, short* __restrict__ Wtp) {
  int idx = blockIdx.x * 256 + threadIdx.x;
  int e = idx >> 7;
  int c = idx & 127;
  int r = sel[c];
  short v = f2bf(W[e * LR + r]);
  Wp [(((e >> 3) << 7) + c) * 8 + (e & 7)] = v;
  Wtp[(((c >> 3) << 12) + e) * 8 + (c & 7)] = v;
}

// PROBE: pure bulk-register-load BW test with gemm1a's exact A pattern.
// No LDS, no MFMA. Writes 1 float/thread into Tpart scratch (overwritten
// by gemm1a afterwards). Its dispatch duration = pattern ceiling.
__global__ __launch_bounds__(256, 3) void probe_kernel(
    const float* __restrict__ base, const float* __restrict__ src,
    float* __restrict__ sink) {
  const int t = threadIdx.x;
  const int w = t >> 6, l = t & 63;
  const int lr = l & 15, lg = l >> 4;
  const int slice = blockIdx.x & 7, tile = blockIdx.x >> 3;
  const int row0 = tile * 64 + w * 16;
  const int k0 = slice * KSLICE;
  const float* bp = base + (size_t)(row0 + lr) * EMBED + k0 + lg * 8;
  const float* sp = src  + (size_t)(row0 + lr) * EMBED + k0 + lg * 8;
  f32x4 acc = {0.f, 0.f, 0.f, 0.f};
  #pragma unroll 1
  for (int it = 0; it < 8; ++it) {
    f32x4 v[8];
    v[0] = *(const f32x4*)(bp + it * 64);
    v[1] = *(const f32x4*)(bp + it * 64 + 4);
    v[2] = *(const f32x4*)(bp + it * 64 + 32);
    v[3] = *(const f32x4*)(bp + it * 64 + 36);
    v[4] = *(const f32x4*)(sp + it * 64);
    v[5] = *(const f32x4*)(sp + it * 64 + 4);
    v[6] = *(const f32x4*)(sp + it * 64 + 32);
    v[7] = *(const f32x4*)(sp + it * 64 + 36);
    #pragma unroll
    for (int j = 0; j < 8; ++j) acc += v[j];
  }
  sink[(size_t)blockIdx.x * 256 + t] = acc[0] + acc[1] + acc[2] + acc[3];
}

// K1a: Tpart[slice] = (src-base)[:, k0:k0+512) @ Wsel[k0:k0+512), :]
// gemm2-shaped: pure register blocking, NO LDS, NO barriers. 1024 blocks
// (128 rowtiles x 8 kslices) x 256 thr; wave = 16 rows x 128 cols.
// 8 iters of K=64: 8 raw A loads + 16 B frag loads into NAMED LIVE ARRAYS
// (forces MLP ~24 like gemm2), then cvt + 16 MFMAs.
template<typename PT>
__global__ __launch_bounds__(256, 3) void gemm1a_kernel(
    const float* __restrict__ base, const float* __restrict__ src,
    const short* __restrict__ Wp, PT* __restrict__ Tpart) {
  const int t = threadIdx.x;
  const int w = t >> 6, l = t & 63;
  const int lr = l & 15, lg = l >> 4;
  const int slice = blockIdx.x & 7, tile = blockIdx.x >> 3;
  const int row0 = tile * 64 + w * 16;
  const int k0 = slice * KSLICE;

  const float* bp = base + (size_t)(row0 + lr) * EMBED + k0 + lg * 8;
  const float* sp = src  + (size_t)(row0 + lr) * EMBED + k0 + lg * 8;
  const short8* wq = (const short8*)Wp + ((size_t)(k0 >> 3) + lg) * 128 + lr;

  f32x4 acc[8];
  #pragma unroll
  for (int c = 0; c < 8; ++c) acc[c] = (f32x4){0.f, 0.f, 0.f, 0.f};

  #pragma unroll 1
  for (int it = 0; it < 8; ++it) {
    // ---- bulk loads (all live simultaneously -> deep MLP) ----
    f32x4 rb0 = *(const f32x4*)(bp + it * 64);
    f32x4 rb1 = *(const f32x4*)(bp + it * 64 + 4);
    f32x4 rb2 = *(const f32x4*)(bp + it * 64 + 32);
    f32x4 rb3 = *(const f32x4*)(bp + it * 64 + 36);
    f32x4 rs0 = *(const f32x4*)(sp + it * 64);
    f32x4 rs1 = *(const f32x4*)(sp + it * 64 + 4);
    f32x4 rs2 = *(const f32x4*)(sp + it * 64 + 32);
    f32x4 rs3 = *(const f32x4*)(sp + it * 64 + 36);
    short8 bf[16];
    #pragma unroll
    for (int ks2 = 0; ks2 < 2; ++ks2)
      #pragma unroll
      for (int c = 0; c < 8; ++c)
        bf[ks2 * 8 + c] = wq[it * 1024 + ks2 * 512 + c * 16];
    // ---- convert ----
    union { short8 v; __hip_bfloat162 h[4]; } u0, u1;
    u0.h[0] = __float22bfloat162_rn(make_float2(rs0[0] - rb0[0], rs0[1] - rb0[1]));
    u0.h[1] = __float22bfloat162_rn(make_float2(rs0[2] - rb0[2], rs0[3] - rb0[3]));
    u0.h[2] = __float22bfloat162_rn(make_float2(rs1[0] - rb1[0], rs1[1] - rb1[1]));
    u0.h[3] = __float22bfloat162_rn(make_float2(rs1[2] - rb1[2], rs1[3] - rb1[3]));
    u1.h[0] = __float22bfloat162_rn(make_float2(rs2[0] - rb2[0], rs2[1] - rb2[1]));
    u1.h[1] = __float22bfloat162_rn(make_float2(rs2[2] - rb2[2], rs2[3] - rb2[3]));
    u1.h[2] = __float22bfloat162_rn(make_float2(rs3[0] - rb3[0], rs3[1] - rb3[1]));
    u1.h[3] = __float22bfloat162_rn(make_float2(rs3[2] - rb3[2], rs3[3] - rb3[3]));
    // ---- MFMAs ----
    #pragma unroll
    for (int c = 0; c < 8; ++c)
      acc[c] = __builtin_amdgcn_mfma_f32_16x16x32_bf16(u0.v, bf[c], acc[c], 0, 0, 0);
    #pragma unroll
    for (int c = 0; c < 8; ++c)
      acc[c] = __builtin_amdgcn_mfma_f32_16x16x32_bf16(u1.v, bf[8 + c], acc[c], 0, 0, 0);
  }

  // lane holds Tpart[slice][row0 + 4lg + r][c*16 + lr]  (layout validated R5/R6)
  PT* o = Tpart + ((size_t)slice * BATCH + row0 + lg * 4) * KSEL + lr;
  #pragma unroll
  for (int c = 0; c < 8; ++c)
    #pragma unroll
    for (int r = 0; r < 4; ++r)
      storept(o + (size_t)r * KSEL + c * 16, acc[c][r]);
}

// K1b: Tp (packed bf16 [kk/8][8192][8]) = sum of 8 Tpart slices
template<typename PT>
__global__ __launch_bounds__(512) void reduce_kernel(
    const PT* __restrict__ Tpart, short* __restrict__ Tp) {
  const int tid = blockIdx.x * 512 + threadIdx.x;   // 0..131071
  const int kkg = tid & 15, row = tid >> 4;
  f32x4 s0 = {0.f, 0.f, 0.f, 0.f}, s1 = {0.f, 0.f, 0.f, 0.f};
  #pragma unroll
  for (int s = 0; s < NSLICE; ++s)
    loadpart(Tpart + ((size_t)s * BATCH + row) * KSEL + kkg * 8, s0, s1);
  short8 o;
  #pragma unroll
  for (int j = 0; j < 4; ++j) { o[j] = f2bf(s0[j]); o[4 + j] = f2bf(s1[j]); }
  *(short8*)(Tp + ((size_t)kkg * BATCH + row) * 8) = o;
}

// K2: out = base + T @ Wsel^T. Block: 64 rows x 256 cols, 4 waves.
__global__ __launch_bounds__(256) void gemm2_kernel(
    const float* __restrict__ base, const short* __restrict__ Tp,
    const short* __restrict__ Wtp, float* __restrict__ out) {
  const int t  = threadIdx.x;
  const int w  = t >> 6, l = t & 63;
  const int lr = l & 15, lg = l >> 4;
  const int mt = blockIdx.x >> 4, nt = blockIdx.x & 15;
  const int row0 = mt * 64;
  const int col0 = nt * 256 + w * 64;

  short8 afr[4][4];
  #pragma unroll
  for (int m = 0; m < 4; ++m)
    #pragma unroll
    for (int ks = 0; ks < 4; ++ks)
      afr[m][ks] = *(const short8*)(Tp + (size_t)(((ks * 4 + lg) << 13) + row0 + m * 16 + lr) * 8);

  f32x4 acc[4][4];
  #pragma unroll
  for (int m = 0; m < 4; ++m)
    #pragma unroll
    for (int nf = 0; nf < 4; ++nf) acc[m][nf] = (f32x4){0.f, 0.f, 0.f, 0.f};

  #pragma unroll
  for (int nf = 0; nf < 4; ++nf) {
    short8 bfr[4];
    #pragma unroll
    for (int ks = 0; ks < 4; ++ks)
      bfr[ks] = *(const short8*)(Wtp + (size_t)(((ks * 4 + lg) << 12) + col0 + nf * 16 + lr) * 8);
    #pragma unroll
    for (int m = 0; m < 4; ++m)
      #pragma unroll
      for (int ks = 0; ks < 4; ++ks)
        acc[m][nf] = __builtin_amdgcn_mfma_f32_16x16x32_bf16(afr[m][ks], bfr[ks], acc[m][nf], 0, 0, 0);
  }

  #pragma unroll
  for (int m = 0; m < 4; ++m)
    #pragma unroll
    for (int r = 0; r < 4; ++r) {
      const size_t row = row0 + m * 16 + lg * 4 + r;
      #pragma unroll
      for (int nf = 0; nf < 4; ++nf) {
        const size_t o = row * EMBED + col0 + nf * 16 + lr;
        out[o] = base[o] + acc[m][nf][r];
      }
    }
}

extern "C" void kernel_launch(void* const* d_in, const int* in_sizes, int n_in,
                              void* d_out, int out_size, void* d_ws, size_t ws_size,
                              hipStream_t stream) {
  const float* base = (const float*)d_in[0];
  const float* src  = (const float*)d_in[1];
  const int*   sub  = (const int*)d_in[2];
  const float* W    = (const float*)d_in[3];
  float* out = (float*)d_out;

  short* Wp  = (short*)d_ws;                       // 1 MB
  short* Wtp = Wp  + EMBED * KSEL;                 // 1 MB
  short* Tp  = Wtp + EMBED * KSEL;                 // 2 MB
  char*  rest = (char*)(Tp + BATCH * KSEL);        // offset 4 MB

  pack_w_kernel<<<EMBED * KSEL / 256, 256, 0, stream>>>(W, sub, Wp, Wtp);
  probe_kernel<<<1024, 256, 0, stream>>>(base, src, (float*)rest);

  const size_t need_f32 = (size_t)4 * 1024 * 1024 +
                          (size_t)NSLICE * BATCH * KSEL * sizeof(float);
  if (ws_size >= need_f32) {
    float* Tpart = (float*)rest;                   // 32 MB
    gemm1a_kernel<float><<<1024, 256, 0, stream>>>(base, src, Wp, Tpart);
    reduce_kernel<float><<<BATCH * 16 / 512, 512, 0, stream>>>(Tpart, Tp);
  } else {
    short* Tpart = (short*)rest;                   // 16 MB
    gemm1a_kernel<short><<<1024, 256, 0, stream>>>(base, src, Wp, Tpart);
    reduce_kernel<short><<<BATCH * 16 / 512, 512, 0, stream>>>(Tpart, Tp);
  }

  gemm2_kernel<<<(BATCH / 64) * 16, 256, 0, stream>>>(base, Tp, Wtp, out);
}

// Round 8
// 135.048 us; speedup vs baseline: 1.4614x; 1.4614x over previous
//
#include <hip/hip_runtime.h>
#include <hip/hip_bf16.h>

typedef __attribute__((ext_vector_type(4))) float  f32x4;
typedef __attribute__((ext_vector_type(8))) short  short8;
typedef unsigned int u32;

#define EMBED 4096
#define LR    512
#define KSEL  128
#define BATCH 8192

__device__ __forceinline__ short f2bf(float x) {
  union { float f; unsigned u; } c; c.f = x;
  unsigned r = c.u + 0x7FFFu + ((c.u >> 16) & 1u);  // RNE
  return (short)(r >> 16);
}
__device__ __forceinline__ void gload16(const void* g, void* l) {
  __builtin_amdgcn_global_load_lds((const __attribute__((address_space(1))) u32*)g,
                                   (__attribute__((address_space(3))) u32*)l, 16, 0, 0);
}

// K0: gather selected columns of W, emit two bf16 MFMA-packed layouts.
// Wp : [e/8][128 cols][8]  (B-operand for GEMM1: kk-dim = embed)
// Wtp: [c/8][4096 e ][8]  (B-operand for GEMM2: kk-dim = sel index)
__global__ __launch_bounds__(256) void pack_w_kernel(
    const float* __restrict__ W, const int* __restrict__ sel,
    short* __restrict__ Wp, short* __restrict__ Wtp) {
  int idx = blockIdx.x * 256 + threadIdx.x;
  int e = idx >> 7;
  int c = idx & 127;
  int r = sel[c];
  short v = f2bf(W[e * LR + r]);
  Wp [(((e >> 3) << 7) + c) * 8 + (e & 7)] = v;
  Wtp[(((c >> 3) << 12) + e) * 8 + (c & 7)] = v;
}

// K1: Tp (packed bf16 [kk/8][8192][8]) = (src - base) @ Wsel
// 512 blocks x 256 thr (4 waves). Block = 16 rows x FULL K (no cross-block
// reduce). BK=256, dbuf LDS 2x32KB. KEY CHANGE vs R2-R7: every global load
// instruction is WAVE-CONTIGUOUS (64 lanes cover 1KB of ONE row) instead of
// 16 scattered 64B segments 16KB apart (probe-proven 1.4 TB/s ceiling).
// LDS[row][c] holds global chunk c^(row&7) (swizzle via source addr, rule 21;
// low-bit XOR so ds_read bank-groups decollide). B-frags issue BEFORE STAGE
// so vmcnt waits on B never drain the staging queue (in-order vmcnt).
__global__ __launch_bounds__(256, 2) void gemm1_kernel(
    const float* __restrict__ base, const float* __restrict__ src,
    const short* __restrict__ Wp, short* __restrict__ Tp) {
  __shared__ __align__(16) char smem[65536];   // 2 bufs x (16 rows x 1KB x 2 arr)
  const int t  = threadIdx.x;
  const int w  = t >> 6, l = t & 63;
  const int lr = l & 15, lg = l >> 4;
  const int row0 = blockIdx.x * 16;

  const int srow = t >> 6;       // base row (0..3), +4 per issue
  const int sc   = t & 63;       // 16B chunk within a 1KB row-slice

  // issue i covers rows 4i..4i+3; wave = one row = 1KB contiguous (swizzle
  // permutes 16B chunks within the same 1KB span -> same lines fetched).
  #define STAGE(s, b) do {                                                  \
    char* d_ = smem + (b) * 32768 + t * 16;                                 \
    _Pragma("unroll")                                                       \
    for (int i = 0; i < 4; ++i) {                                           \
      const int row = i * 4 + srow;                                         \
      const size_t go = (size_t)(row0 + row) * EMBED + (s) * 256            \
                        + ((sc ^ (row & 7)) << 2);                          \
      gload16(base + go, d_ + i * 4096);                                    \
      gload16(src  + go, d_ + 16384 + i * 4096);                            \
    }                                                                       \
  } while (0)

  const short8* wq = (const short8*)Wp;
  f32x4 acc0 = {0.f, 0.f, 0.f, 0.f}, acc1 = {0.f, 0.f, 0.f, 0.f};

  STAGE(0, 0);
  int b = 0;
  for (int s = 0; s < 16; ++s) {
    __syncthreads();                         // buf b staged (vmcnt drain here)
    // --- B-frag loads for THIS chunk: issued FIRST so they are OLDER than
    //     the next STAGE in the vmcnt queue; consuming them leaves STAGE
    //     in flight. L2-resident (Wp = 1MB). ---
    const int kc = s * 256;
    short8 bf[16];
    #pragma unroll
    for (int kstep = 0; kstep < 8; ++kstep) {
      const int kg = ((kc + kstep * 32) >> 3) + lg;
      bf[kstep * 2]     = wq[(size_t)kg * 128 + w * 32 + lr];
      bf[kstep * 2 + 1] = wq[(size_t)kg * 128 + w * 32 + 16 + lr];
    }
    if (s < 15) STAGE(s + 1, b ^ 1);         // flies under this chunk's compute
    // --- compute: pure LDS + VALU + MFMA ---
    const char* tb = smem + b * 32768 + lr * 1024;
    #pragma unroll
    for (int kstep = 0; kstep < 8; ++kstep) {
      const int j0 = (kstep * 8 + lg * 2)     ^ (lr & 7);
      const int j1 = (kstep * 8 + lg * 2 + 1) ^ (lr & 7);
      f32x4 b0 = *(const f32x4*)(tb + j0 * 16);
      f32x4 b1 = *(const f32x4*)(tb + j1 * 16);
      f32x4 s0 = *(const f32x4*)(tb + 16384 + j0 * 16);
      f32x4 s1 = *(const f32x4*)(tb + 16384 + j1 * 16);
      union { short8 v; __hip_bfloat162 h[4]; } u;
      u.h[0] = __float22bfloat162_rn(make_float2(s0[0] - b0[0], s0[1] - b0[1]));
      u.h[1] = __float22bfloat162_rn(make_float2(s0[2] - b0[2], s0[3] - b0[3]));
      u.h[2] = __float22bfloat162_rn(make_float2(s1[0] - b1[0], s1[1] - b1[1]));
      u.h[3] = __float22bfloat162_rn(make_float2(s1[2] - b1[2], s1[3] - b1[3]));
      acc0 = __builtin_amdgcn_mfma_f32_16x16x32_bf16(u.v, bf[kstep * 2],     acc0, 0, 0, 0);
      acc1 = __builtin_amdgcn_mfma_f32_16x16x32_bf16(u.v, bf[kstep * 2 + 1], acc1, 0, 0, 0);
    }
    b ^= 1;
  }
  #undef STAGE

  // lane holds T[row0 + 4lg + r][kk = w*32 + ct*16 + lr]  (R1/R2-verified form)
  #pragma unroll
  for (int ct = 0; ct < 2; ++ct) {
    f32x4 a = ct ? acc1 : acc0;
    const int kk = w * 32 + ct * 16 + lr;
    short* dst = Tp + (size_t)(((kk >> 3) << 13) + row0 + (lg << 2)) * 8 + (kk & 7);
    #pragma unroll
    for (int r = 0; r < 4; ++r) dst[r * 8] = f2bf(a[r]);
  }
}

// K2: out = base + T @ Wsel^T. Block: 64 rows x 256 cols, 4 waves.
__global__ __launch_bounds__(256) void gemm2_kernel(
    const float* __restrict__ base, const short* __restrict__ Tp,
    const short* __restrict__ Wtp, float* __restrict__ out) {
  const int t  = threadIdx.x;
  const int w  = t >> 6, l = t & 63;
  const int lr = l & 15, lg = l >> 4;
  const int mt = blockIdx.x >> 4, nt = blockIdx.x & 15;
  const int row0 = mt * 64;
  const int col0 = nt * 256 + w * 64;

  short8 afr[4][4];
  #pragma unroll
  for (int m = 0; m < 4; ++m)
    #pragma unroll
    for (int ks = 0; ks < 4; ++ks)
      afr[m][ks] = *(const short8*)(Tp + (size_t)(((ks * 4 + lg) << 13) + row0 + m * 16 + lr) * 8);

  f32x4 acc[4][4];
  #pragma unroll
  for (int m = 0; m < 4; ++m)
    #pragma unroll
    for (int nf = 0; nf < 4; ++nf) acc[m][nf] = (f32x4){0.f, 0.f, 0.f, 0.f};

  #pragma unroll
  for (int nf = 0; nf < 4; ++nf) {
    short8 bfr[4];
    #pragma unroll
    for (int ks = 0; ks < 4; ++ks)
      bfr[ks] = *(const short8*)(Wtp + (size_t)(((ks * 4 + lg) << 12) + col0 + nf * 16 + lr) * 8);
    #pragma unroll
    for (int m = 0; m < 4; ++m)
      #pragma unroll
      for (int ks = 0; ks < 4; ++ks)
        acc[m][nf] = __builtin_amdgcn_mfma_f32_16x16x32_bf16(afr[m][ks], bfr[ks], acc[m][nf], 0, 0, 0);
  }

  #pragma unroll
  for (int m = 0; m < 4; ++m)
    #pragma unroll
    for (int r = 0; r < 4; ++r) {
      const size_t row = row0 + m * 16 + lg * 4 + r;
      #pragma unroll
      for (int nf = 0; nf < 4; ++nf) {
        const size_t o = row * EMBED + col0 + nf * 16 + lr;
        out[o] = base[o] + acc[m][nf][r];
      }
    }
}

extern "C" void kernel_launch(void* const* d_in, const int* in_sizes, int n_in,
                              void* d_out, int out_size, void* d_ws, size_t ws_size,
                              hipStream_t stream) {
  const float* base = (const float*)d_in[0];
  const float* src  = (const float*)d_in[1];
  const int*   sub  = (const int*)d_in[2];
  const float* W    = (const float*)d_in[3];
  float* out = (float*)d_out;

  short* Wp  = (short*)d_ws;                       // 1 MB
  short* Wtp = Wp  + EMBED * KSEL;                 // 1 MB
  short* Tp  = Wtp + EMBED * KSEL;                 // 2 MB

  pack_w_kernel<<<EMBED * KSEL / 256, 256, 0, stream>>>(W, sub, Wp, Wtp);
  gemm1_kernel<<<BATCH / 16, 256, 0, stream>>>(base, src, Wp, Tp);
  gemm2_kernel<<<(BATCH / 64) * 16, 256, 0, stream>>>(base, Tp, Wtp, out);
}